// Round 2
// baseline (555.053 us; speedup 1.0000x reference)
//
#include <hip/hip_runtime.h>
#include <math.h>

#define N 8192
#define D 512
#define BT 64
#define BK 32
#define TPAD 68   // k-major LDS row stride (floats); 272B keeps float4 align, breaks power-of-2 bank aliasing
#define NEG_INF_SENT (-3.0e38f)

__global__ __launch_bounds__(256) void rowsq_kernel(const float* __restrict__ x,
                                                    float* __restrict__ sq) {
    int row = blockIdx.x * 4 + (threadIdx.x >> 6);
    int lane = threadIdx.x & 63;
    const float* xr = x + (size_t)row * D;
    float s = 0.f;
#pragma unroll
    for (int k = 0; k < D / 64; ++k) {
        float v = xr[lane + k * 64];
        s += v * v;
    }
#pragma unroll
    for (int off = 32; off > 0; off >>= 1) s += __shfl_down(s, off, 64);
    if (lane == 0) sq[row] = s;
}

// logsumexp merge: (m1,s1) <- (m1,s1) ⊕ (m2,s2)
__device__ inline void lse_merge(float& m1, float& s1, float m2, float s2) {
    float M = fmaxf(m1, m2);
    s1 = s1 * __expf(m1 - M) + s2 * __expf(m2 - M);
    m1 = M;
}

__global__ __launch_bounds__(256) void pair_kernel(const float* __restrict__ x,
                                                   const float* __restrict__ sq,
                                                   float* __restrict__ bm,
                                                   float* __restrict__ bs) {
    __shared__ __align__(16) float As[BK][TPAD];
    __shared__ __align__(16) float Bs[BK][TPAD];

    const int T = N / BT;  // 128
    const int b = blockIdx.x;
    // decode linear index -> (bi, bj), bi <= bj (upper-triangle tile set incl. diagonal)
    int bi = (int)((2 * T + 1 - sqrtf((float)((2 * T + 1) * (2 * T + 1) - 8 * b))) * 0.5f);
    if (bi < 0) bi = 0;
    if (bi > T - 1) bi = T - 1;
    while ((bi + 1) * (2 * T - bi) / 2 <= b) ++bi;
    while (bi * (2 * T - bi + 1) / 2 > b) --bi;
    const int bj = bi + (b - bi * (2 * T - bi + 1) / 2);

    const int i0 = bi * BT, j0 = bj * BT;
    const int tid = threadIdx.x;
    const int tx = tid & 15, ty = tid >> 4;

    float dot[4][4];
#pragma unroll
    for (int r = 0; r < 4; ++r)
#pragma unroll
        for (int c = 0; c < 4; ++c) dot[r][c] = 0.f;

    for (int k0 = 0; k0 < D; k0 += BK) {
        // stage A (rows i0..) and B (rows j0..), cols k0..k0+31, k-major in LDS
#pragma unroll
        for (int h = 0; h < 2; ++h) {
            int f = tid + h * 256;       // float4 index 0..511
            int row = f >> 3;            // 0..63
            int kc = (f & 7) << 2;       // 0,4,...,28
            const float4 a4 = *(const float4*)(x + (size_t)(i0 + row) * D + k0 + kc);
            As[kc + 0][row] = a4.x; As[kc + 1][row] = a4.y;
            As[kc + 2][row] = a4.z; As[kc + 3][row] = a4.w;
            const float4 b4 = *(const float4*)(x + (size_t)(j0 + row) * D + k0 + kc);
            Bs[kc + 0][row] = b4.x; Bs[kc + 1][row] = b4.y;
            Bs[kc + 2][row] = b4.z; Bs[kc + 3][row] = b4.w;
        }
        __syncthreads();
#pragma unroll
        for (int k = 0; k < BK; ++k) {
            float4 a4 = *(const float4*)&As[k][ty * 4];
            float4 b4 = *(const float4*)&Bs[k][tx * 4];
            float ar[4] = {a4.x, a4.y, a4.z, a4.w};
            float br[4] = {b4.x, b4.y, b4.z, b4.w};
#pragma unroll
            for (int r = 0; r < 4; ++r)
#pragma unroll
                for (int c = 0; c < 4; ++c)
                    dot[r][c] = fmaf(ar[r], br[c], dot[r][c]);
        }
        __syncthreads();
    }

    // per-thread online logsumexp over t = -2*d2 for this thread's 16 pairs (strict upper tri)
    float m = NEG_INF_SENT, s = 0.f;
#pragma unroll
    for (int r = 0; r < 4; ++r) {
        int i = i0 + ty * 4 + r;
        float sqi = sq[i];
#pragma unroll
        for (int c = 0; c < 4; ++c) {
            int j = j0 + tx * 4 + c;
            if (j > i) {
                float d2 = fmaxf(sqi + sq[j] - 2.f * dot[r][c], 0.f);
                float t = -2.0f * d2;
                if (t > m) { s = s * __expf(m - t) + 1.0f; m = t; }
                else       { s += __expf(t - m); }
            }
        }
    }

    // wave merge
#pragma unroll
    for (int off = 32; off > 0; off >>= 1) {
        float m2 = __shfl_down(m, off, 64);
        float s2 = __shfl_down(s, off, 64);
        lse_merge(m, s, m2, s2);
    }
    __shared__ float rm[4], rs[4];
    if ((tid & 63) == 0) { rm[tid >> 6] = m; rs[tid >> 6] = s; }
    __syncthreads();
    if (tid == 0) {
#pragma unroll
        for (int w = 1; w < 4; ++w) lse_merge(rm[0], rs[0], rm[w], rs[w]);
        bm[b] = rm[0];
        bs[b] = rs[0];
    }
}

__global__ __launch_bounds__(256) void finalize_kernel(const float* __restrict__ bm,
                                                       const float* __restrict__ bs,
                                                       int nblocks,
                                                       float* __restrict__ out) {
    const int tid = threadIdx.x;
    float m = NEG_INF_SENT, s = 0.f;
    for (int b = tid; b < nblocks; b += 256) lse_merge(m, s, bm[b], bs[b]);
#pragma unroll
    for (int off = 32; off > 0; off >>= 1) {
        float m2 = __shfl_down(m, off, 64);
        float s2 = __shfl_down(s, off, 64);
        lse_merge(m, s, m2, s2);
    }
    __shared__ float rm[4], rs[4];
    if ((tid & 63) == 0) { rm[tid >> 6] = m; rs[tid >> 6] = s; }
    __syncthreads();
    if (tid == 0) {
#pragma unroll
        for (int w = 1; w < 4; ++w) lse_merge(rm[0], rs[0], rm[w], rs[w]);
        // log(sum_e / P) = M + log(S) - log(P), computed without underflow
        const float log_num_pairs = 17.328536f;  // log(8192*8191/2)
        out[0] = rm[0] + logf(rs[0]) - log_num_pairs;
    }
}

extern "C" void kernel_launch(void* const* d_in, const int* in_sizes, int n_in,
                              void* d_out, int out_size, void* d_ws, size_t ws_size,
                              hipStream_t stream) {
    const float* x = (const float*)d_in[0];
    float* out = (float*)d_out;
    float* ws = (float*)d_ws;

    const int T = N / BT;
    const int nblocks = T * (T + 1) / 2;  // 8256
    float* bm = ws;                        // [8256]
    float* bs = ws + nblocks;              // [8256]
    float* sq = ws + 2 * nblocks;          // [8192]

    rowsq_kernel<<<N / 4, 256, 0, stream>>>(x, sq);
    pair_kernel<<<nblocks, 256, 0, stream>>>(x, sq, bm, bs);
    finalize_kernel<<<1, 256, 0, stream>>>(bm, bs, nblocks, out);
}

// Round 3
// 169.270 us; speedup vs baseline: 3.2791x; 3.2791x over previous
//
#include <hip/hip_runtime.h>
#include <math.h>

#define N 8192
#define D 512
#define NEG_INF_SENT (-3.0e38f)

typedef __attribute__((ext_vector_type(8))) short short8x;   // 8 bf16 in 4 VGPRs
typedef __attribute__((ext_vector_type(4))) float f32x4;

#define AS1 __attribute__((address_space(1)))
#define AS3 __attribute__((address_space(3)))

__device__ inline void lse_merge(float& m1, float& s1, float m2, float s2) {
    float M = fmaxf(m1, m2);
    s1 = s1 * __expf(m1 - M) + s2 * __expf(m2 - M);
    m1 = M;
}

__device__ inline unsigned short bf16_rne(float f) {
    union { float f; unsigned u; } c; c.f = f;
    unsigned u = c.u;
    return (unsigned short)((u + 0x7FFFu + ((u >> 16) & 1u)) >> 16);
}

// ---- fused cast + row-sumsq: one wave per row --------------------------------
__global__ __launch_bounds__(256) void cast_rowsq_kernel(const float* __restrict__ x,
                                                         short* __restrict__ xb,
                                                         float* __restrict__ sq) {
    int row = blockIdx.x * 4 + (threadIdx.x >> 6);
    int lane = threadIdx.x & 63;
    const float4* xr = (const float4*)(x + (size_t)row * D);
    float4 a = xr[lane * 2], b = xr[lane * 2 + 1];
    float v[8] = {a.x, a.y, a.z, a.w, b.x, b.y, b.z, b.w};
    float s = 0.f;
    unsigned short h[8];
#pragma unroll
    for (int e = 0; e < 8; ++e) { s += v[e] * v[e]; h[e] = bf16_rne(v[e]); }
    uint4 pk;
    pk.x = (unsigned)h[0] | ((unsigned)h[1] << 16);
    pk.y = (unsigned)h[2] | ((unsigned)h[3] << 16);
    pk.z = (unsigned)h[4] | ((unsigned)h[5] << 16);
    pk.w = (unsigned)h[6] | ((unsigned)h[7] << 16);
    ((uint4*)xb)[(size_t)row * 64 + lane] = pk;
#pragma unroll
    for (int off = 32; off > 0; off >>= 1) s += __shfl_down(s, off, 64);
    if (lane == 0) sq[row] = s;
}

// ---- MFMA pair kernel: 128x128 tile, 16x16x32 bf16, fragment-order LDS -------
__global__ __launch_bounds__(256) void pair_mfma_kernel(const short* __restrict__ xb,
                                                        const float* __restrict__ sq,
                                                        float* __restrict__ bm,
                                                        float* __restrict__ bs) {
    // LDS in MFMA-fragment order: [tile16][kstep][lane*8 bf16] -> 16 KB each
    __shared__ __align__(16) short A_lds[8][2][512];
    __shared__ __align__(16) short B_lds[8][2][512];

    const int T = N / 128;  // 64
    const int b = blockIdx.x;
    int bi = (int)((2 * T + 1 - sqrtf((float)((2 * T + 1) * (2 * T + 1) - 8 * b))) * 0.5f);
    if (bi < 0) bi = 0;
    if (bi > T - 1) bi = T - 1;
    while ((bi + 1) * (2 * T - bi) / 2 <= b) ++bi;
    while (bi * (2 * T - bi + 1) / 2 > b) --bi;
    const int bj = bi + (b - bi * (2 * T - bi + 1) / 2);
    const int i0 = bi * 128, j0 = bj * 128;

    const int tid = threadIdx.x;
    const int lane = tid & 63;
    const int w = tid >> 6;          // wave 0..3
    const int wy = w >> 1, wx = w & 1;
    const int frow = lane & 15;      // fragment row/col
    const int kq = lane >> 4;        // k-quad 0..3

    f32x4 acc[4][4];
#pragma unroll
    for (int mi = 0; mi < 4; ++mi)
#pragma unroll
        for (int ni = 0; ni < 4; ++ni) acc[mi][ni] = (f32x4){0.f, 0.f, 0.f, 0.f};

    for (int k0 = 0; k0 < D; k0 += 64) {
        // stage 32 fragments (16 A + 16 B), 8 per wave, 16B per lane DMA
#pragma unroll
        for (int q = 0; q < 8; ++q) {
            int f = (w << 3) | q;            // 0..31, wave-uniform
            int mt = (f >> 1) & 7;
            int ks = f & 1;
            int grow = (f < 16 ? i0 : j0) + mt * 16 + frow;
            const short* g = xb + (size_t)grow * D + k0 + ks * 32 + kq * 8;
            short* l = (f < 16) ? &A_lds[mt][ks][0] : &B_lds[mt][ks][0];
            __builtin_amdgcn_global_load_lds((const AS1 void*)g, (AS3 void*)l, 16, 0, 0);
        }
        __syncthreads();
#pragma unroll
        for (int ks = 0; ks < 2; ++ks) {
            short8x a_frag[4], b_frag[4];
#pragma unroll
            for (int t = 0; t < 4; ++t) {
                a_frag[t] = *(const short8x*)&A_lds[wy * 4 + t][ks][lane << 3];
                b_frag[t] = *(const short8x*)&B_lds[wx * 4 + t][ks][lane << 3];
            }
#pragma unroll
            for (int mi = 0; mi < 4; ++mi)
#pragma unroll
                for (int ni = 0; ni < 4; ++ni)
                    acc[mi][ni] = __builtin_amdgcn_mfma_f32_16x16x32_bf16(
                        a_frag[mi], b_frag[ni], acc[mi][ni], 0, 0, 0);
        }
        __syncthreads();
    }

    // epilogue: d2 = sq[i]+sq[j]-2*dot ; online LSE over t=-2*d2
    const int rbase = kq * 4;        // C/D: row=(lane>>4)*4+reg, col=lane&15
    float m = NEG_INF_SENT, s = 0.f;
    float sqj[4];
#pragma unroll
    for (int ni = 0; ni < 4; ++ni) sqj[ni] = sq[j0 + wx * 64 + ni * 16 + frow];
    const bool offdiag = (bi != bj);
#pragma unroll
    for (int mi = 0; mi < 4; ++mi) {
#pragma unroll
        for (int r = 0; r < 4; ++r) {
            int i = i0 + wy * 64 + mi * 16 + rbase + r;
            float sqi = sq[i];
#pragma unroll
            for (int ni = 0; ni < 4; ++ni) {
                int j = j0 + wx * 64 + ni * 16 + frow;
                if (offdiag || j > i) {
                    float d2 = fmaxf(sqi + sqj[ni] - 2.f * acc[mi][ni][r], 0.f);
                    float t = -2.0f * d2;
                    if (t > m) { s = s * __expf(m - t) + 1.0f; m = t; }
                    else       { s += __expf(t - m); }
                }
            }
        }
    }
#pragma unroll
    for (int off = 32; off > 0; off >>= 1) {
        float m2 = __shfl_down(m, off, 64);
        float s2 = __shfl_down(s, off, 64);
        lse_merge(m, s, m2, s2);
    }
    __shared__ float rm[4], rs[4];
    if (lane == 0) { rm[w] = m; rs[w] = s; }
    __syncthreads();
    if (tid == 0) {
#pragma unroll
        for (int v = 1; v < 4; ++v) lse_merge(rm[0], rs[0], rm[v], rs[v]);
        bm[b] = rm[0];
        bs[b] = rs[0];
    }
}

__global__ __launch_bounds__(256) void finalize_kernel(const float* __restrict__ bm,
                                                       const float* __restrict__ bs,
                                                       int nblocks,
                                                       float* __restrict__ out) {
    const int tid = threadIdx.x;
    float m = NEG_INF_SENT, s = 0.f;
    for (int b = tid; b < nblocks; b += 256) lse_merge(m, s, bm[b], bs[b]);
#pragma unroll
    for (int off = 32; off > 0; off >>= 1) {
        float m2 = __shfl_down(m, off, 64);
        float s2 = __shfl_down(s, off, 64);
        lse_merge(m, s, m2, s2);
    }
    __shared__ float rm[4], rs[4];
    if ((tid & 63) == 0) { rm[tid >> 6] = m; rs[tid >> 6] = s; }
    __syncthreads();
    if (tid == 0) {
#pragma unroll
        for (int v = 1; v < 4; ++v) lse_merge(rm[0], rs[0], rm[v], rs[v]);
        const float log_num_pairs = 17.3285362f;  // log(8192*8191/2)
        out[0] = rm[0] + logf(rs[0]) - log_num_pairs;
    }
}

// ---------------- fp32 fallback (round-2 kernels) if ws too small -------------
#define BT 64
#define BK 32
#define TPAD 68

__global__ __launch_bounds__(256) void rowsq_kernel(const float* __restrict__ x,
                                                    float* __restrict__ sq) {
    int row = blockIdx.x * 4 + (threadIdx.x >> 6);
    int lane = threadIdx.x & 63;
    const float* xr = x + (size_t)row * D;
    float s = 0.f;
#pragma unroll
    for (int k = 0; k < D / 64; ++k) { float v = xr[lane + k * 64]; s += v * v; }
#pragma unroll
    for (int off = 32; off > 0; off >>= 1) s += __shfl_down(s, off, 64);
    if (lane == 0) sq[row] = s;
}

__global__ __launch_bounds__(256) void pair_kernel(const float* __restrict__ x,
                                                   const float* __restrict__ sq,
                                                   float* __restrict__ bm,
                                                   float* __restrict__ bs) {
    __shared__ __align__(16) float As[BK][TPAD];
    __shared__ __align__(16) float Bs[BK][TPAD];
    const int T = N / BT;
    const int b = blockIdx.x;
    int bi = (int)((2 * T + 1 - sqrtf((float)((2 * T + 1) * (2 * T + 1) - 8 * b))) * 0.5f);
    if (bi < 0) bi = 0;
    if (bi > T - 1) bi = T - 1;
    while ((bi + 1) * (2 * T - bi) / 2 <= b) ++bi;
    while (bi * (2 * T - bi + 1) / 2 > b) --bi;
    const int bj = bi + (b - bi * (2 * T - bi + 1) / 2);
    const int i0 = bi * BT, j0 = bj * BT;
    const int tid = threadIdx.x;
    const int tx = tid & 15, ty = tid >> 4;
    float dot[4][4];
#pragma unroll
    for (int r = 0; r < 4; ++r)
#pragma unroll
        for (int c = 0; c < 4; ++c) dot[r][c] = 0.f;
    for (int k0 = 0; k0 < D; k0 += BK) {
#pragma unroll
        for (int h = 0; h < 2; ++h) {
            int f = tid + h * 256;
            int row = f >> 3;
            int kc = (f & 7) << 2;
            const float4 a4 = *(const float4*)(x + (size_t)(i0 + row) * D + k0 + kc);
            As[kc + 0][row] = a4.x; As[kc + 1][row] = a4.y;
            As[kc + 2][row] = a4.z; As[kc + 3][row] = a4.w;
            const float4 b4 = *(const float4*)(x + (size_t)(j0 + row) * D + k0 + kc);
            Bs[kc + 0][row] = b4.x; Bs[kc + 1][row] = b4.y;
            Bs[kc + 2][row] = b4.z; Bs[kc + 3][row] = b4.w;
        }
        __syncthreads();
#pragma unroll
        for (int k = 0; k < BK; ++k) {
            float4 a4 = *(const float4*)&As[k][ty * 4];
            float4 b4 = *(const float4*)&Bs[k][tx * 4];
            float ar[4] = {a4.x, a4.y, a4.z, a4.w};
            float br[4] = {b4.x, b4.y, b4.z, b4.w};
#pragma unroll
            for (int r = 0; r < 4; ++r)
#pragma unroll
                for (int c = 0; c < 4; ++c) dot[r][c] = fmaf(ar[r], br[c], dot[r][c]);
        }
        __syncthreads();
    }
    float m = NEG_INF_SENT, s = 0.f;
#pragma unroll
    for (int r = 0; r < 4; ++r) {
        int i = i0 + ty * 4 + r;
        float sqi = sq[i];
#pragma unroll
        for (int c = 0; c < 4; ++c) {
            int j = j0 + tx * 4 + c;
            if (j > i) {
                float d2 = fmaxf(sqi + sq[j] - 2.f * dot[r][c], 0.f);
                float t = -2.0f * d2;
                if (t > m) { s = s * __expf(m - t) + 1.0f; m = t; }
                else       { s += __expf(t - m); }
            }
        }
    }
#pragma unroll
    for (int off = 32; off > 0; off >>= 1) {
        float m2 = __shfl_down(m, off, 64);
        float s2 = __shfl_down(s, off, 64);
        lse_merge(m, s, m2, s2);
    }
    __shared__ float rm[4], rs[4];
    if ((tid & 63) == 0) { rm[tid >> 6] = m; rs[tid >> 6] = s; }
    __syncthreads();
    if (tid == 0) {
#pragma unroll
        for (int v = 1; v < 4; ++v) lse_merge(rm[0], rs[0], rm[v], rs[v]);
        bm[b] = rm[0];
        bs[b] = rs[0];
    }
}

extern "C" void kernel_launch(void* const* d_in, const int* in_sizes, int n_in,
                              void* d_out, int out_size, void* d_ws, size_t ws_size,
                              hipStream_t stream) {
    const float* x = (const float*)d_in[0];
    float* out = (float*)d_out;

    const int Tm = N / 128;
    const int nb_mfma = Tm * (Tm + 1) / 2;           // 2080
    const size_t xb_bytes = (size_t)N * D * sizeof(short);   // 8 MB
    const size_t need = xb_bytes + (size_t)(N + 2 * nb_mfma) * sizeof(float) + 256;

    if (ws_size >= need) {
        short* xb = (short*)d_ws;
        float* sq = (float*)((char*)d_ws + xb_bytes);
        float* bm = sq + N;
        float* bs = bm + nb_mfma;
        cast_rowsq_kernel<<<N / 4, 256, 0, stream>>>(x, xb, sq);
        pair_mfma_kernel<<<nb_mfma, 256, 0, stream>>>(xb, sq, bm, bs);
        finalize_kernel<<<1, 256, 0, stream>>>(bm, bs, nb_mfma, out);
    } else {
        float* ws = (float*)d_ws;
        const int T = N / BT;
        const int nblocks = T * (T + 1) / 2;          // 8256
        float* bm = ws;
        float* bs = ws + nblocks;
        float* sq = ws + 2 * nblocks;
        rowsq_kernel<<<N / 4, 256, 0, stream>>>(x, sq);
        pair_kernel<<<nblocks, 256, 0, stream>>>(x, sq, bm, bs);
        finalize_kernel<<<1, 256, 0, stream>>>(bm, bs, nblocks, out);
    }
}